// Round 1
// baseline (908.062 us; speedup 1.0000x reference)
//
#include <hip/hip_runtime.h>

// SIGN model: N=50000, E=800000, CIN=64, HOPS=3, HID=256, COUT=64
// z layout: [N, 256] row-major; col-block k (64 wide) = hop-k embedding (k=0 is x).

#define ZW 256
#define NCH 64

__global__ void init_kernel(const float* __restrict__ x, float* __restrict__ z,
                            float* __restrict__ d, int N) {
    int total = N * ZW;
    int stride = gridDim.x * blockDim.x;
    for (int idx = blockIdx.x * blockDim.x + threadIdx.x; idx < total; idx += stride) {
        int n = idx >> 8;
        int c = idx & 255;
        z[idx] = (c < NCH) ? x[n * NCH + c] : 0.0f;
    }
    for (int idx = blockIdx.x * blockDim.x + threadIdx.x; idx < N; idx += stride)
        d[idx] = 0.0f;
}

__global__ void degree_kernel(const int* __restrict__ col, float* __restrict__ d, int E) {
    int stride = gridDim.x * blockDim.x;
    for (int e = blockIdx.x * blockDim.x + threadIdx.x; e < E; e += stride)
        atomicAdd(&d[col[e]], 1.0f);
}

__global__ void value_kernel(const int* __restrict__ row, const int* __restrict__ col,
                             const float* __restrict__ d, float* __restrict__ val, int E) {
    int stride = gridDim.x * blockDim.x;
    for (int e = blockIdx.x * blockDim.x + threadIdx.x; e < E; e += stride) {
        float dc = d[col[e]];
        float dr = d[row[e]];
        float v = 0.0f;
        if (dc > 0.0f && dr > 0.0f) v = 1.0f / (sqrtf(dc) * sqrtf(dr));
        val[e] = v;
    }
}

// One 64-lane wave per edge; lane = channel. Coalesced 256B gather + 64 consecutive atomics.
__global__ void spmm_kernel(const int* __restrict__ row, const int* __restrict__ col,
                            const float* __restrict__ val,
                            const float* __restrict__ zin, float* __restrict__ zout, int E) {
    int lane = threadIdx.x & 63;
    int wave = (blockIdx.x * blockDim.x + threadIdx.x) >> 6;
    int nwaves = (gridDim.x * blockDim.x) >> 6;
    for (int e = wave; e < E; e += nwaves) {
        float v = val[e];
        if (v == 0.0f) continue;          // wave-uniform branch
        int r = row[e];
        int c = col[e];
        float h = zin[r * ZW + lane];
        atomicAdd(&zout[c * ZW + lane], v * h);
    }
}

// C[M,Ncol] = act(A[M,256] @ W[256,Ncol] + bias).  BM=BN=64, BK=16, 256 thr, 4x4/thread.
template <int RELU>
__global__ __launch_bounds__(256) void gemm_kernel(const float* __restrict__ A,
                                                   const float* __restrict__ W,
                                                   const float* __restrict__ bias,
                                                   float* __restrict__ C, int M, int Ncol) {
    const int K = 256;
    __shared__ float As[64][17];   // [m][k], +1 pad
    __shared__ float Bs[16][64];   // [k][n]

    int bm = blockIdx.y * 64;
    int bn = blockIdx.x * 64;
    int tid = threadIdx.x;
    int tx = tid & 15;
    int ty = tid >> 4;

    float acc[4][4] = {};

    int arow = tid >> 2;           // 0..63
    int aq   = (tid & 3) * 4;      // 0,4,8,12
    int brow = tid >> 4;           // 0..15
    int bq   = (tid & 15) * 4;     // 0..60

    for (int k0 = 0; k0 < K; k0 += 16) {
        float4 av = make_float4(0.f, 0.f, 0.f, 0.f);
        int gr = bm + arow;
        if (gr < M) av = *reinterpret_cast<const float4*>(A + gr * K + k0 + aq);
        As[arow][aq + 0] = av.x;
        As[arow][aq + 1] = av.y;
        As[arow][aq + 2] = av.z;
        As[arow][aq + 3] = av.w;

        float4 bv = *reinterpret_cast<const float4*>(W + (k0 + brow) * Ncol + bn + bq);
        *reinterpret_cast<float4*>(&Bs[brow][bq]) = bv;

        __syncthreads();

#pragma unroll
        for (int kk = 0; kk < 16; ++kk) {
            float a0 = As[ty * 4 + 0][kk];
            float a1 = As[ty * 4 + 1][kk];
            float a2 = As[ty * 4 + 2][kk];
            float a3 = As[ty * 4 + 3][kk];
            float b0 = Bs[kk][tx * 4 + 0];
            float b1 = Bs[kk][tx * 4 + 1];
            float b2 = Bs[kk][tx * 4 + 2];
            float b3 = Bs[kk][tx * 4 + 3];
            acc[0][0] += a0 * b0; acc[0][1] += a0 * b1; acc[0][2] += a0 * b2; acc[0][3] += a0 * b3;
            acc[1][0] += a1 * b0; acc[1][1] += a1 * b1; acc[1][2] += a1 * b2; acc[1][3] += a1 * b3;
            acc[2][0] += a2 * b0; acc[2][1] += a2 * b1; acc[2][2] += a2 * b2; acc[2][3] += a2 * b3;
            acc[3][0] += a3 * b0; acc[3][1] += a3 * b1; acc[3][2] += a3 * b2; acc[3][3] += a3 * b3;
        }
        __syncthreads();
    }

#pragma unroll
    for (int i = 0; i < 4; ++i) {
        int gr = bm + ty * 4 + i;
        if (gr >= M) continue;
#pragma unroll
        for (int j = 0; j < 4; ++j) {
            int gc = bn + tx * 4 + j;
            float v = acc[i][j] + bias[gc];
            if (RELU) v = fmaxf(v, 0.0f);
            C[gr * Ncol + gc] = v;
        }
    }
}

extern "C" void kernel_launch(void* const* d_in, const int* in_sizes, int n_in,
                              void* d_out, int out_size, void* d_ws, size_t ws_size,
                              hipStream_t stream) {
    const float* x  = (const float*)d_in[0];
    const int* ei   = (const int*)d_in[1];
    const float* W0 = (const float*)d_in[2];
    const float* b0 = (const float*)d_in[3];
    const float* W1 = (const float*)d_in[4];
    const float* b1 = (const float*)d_in[5];
    const float* W2 = (const float*)d_in[6];
    const float* b2 = (const float*)d_in[7];
    float* out = (float*)d_out;

    const int N = in_sizes[0] / NCH;      // 50000
    const int E = in_sizes[1] / 2;        // 800000
    const int* row = ei;
    const int* col = ei + E;

    // workspace layout (floats)
    float* z   = (float*)d_ws;            // N*256
    float* zt  = z + (size_t)N * ZW;      // N*256
    float* deg = zt + (size_t)N * ZW;     // N
    float* val = deg + N;                 // E

    const int TB = 256;

    init_kernel<<<2048, TB, 0, stream>>>(x, z, deg, N);
    degree_kernel<<<1024, TB, 0, stream>>>(col, deg, E);
    value_kernel<<<1024, TB, 0, stream>>>(row, col, deg, val, E);

    // 3 hops: hop k reads z col-block k-1, scatter-adds into col-block k
    for (int hop = 1; hop <= 3; ++hop) {
        const float* zin = z + (hop - 1) * NCH;
        float* zout      = z + hop * NCH;
        spmm_kernel<<<2048, TB, 0, stream>>>(row, col, val, zin, zout, E);
    }

    dim3 g1(ZW / 64, (N + 63) / 64);
    gemm_kernel<1><<<g1, TB, 0, stream>>>(z, W0, b0, zt, N, ZW);      // z  -> zt (relu)
    gemm_kernel<1><<<g1, TB, 0, stream>>>(zt, W1, b1, z, N, ZW);      // zt -> z  (relu)
    dim3 g3(NCH / 64, (N + 63) / 64);
    gemm_kernel<0><<<g3, TB, 0, stream>>>(z, W2, b2, out, N, NCH);    // z  -> out
}

// Round 2
// 619.401 us; speedup vs baseline: 1.4660x; 1.4660x over previous
//
#include <hip/hip_runtime.h>

// SIGN model: N=50000, E=800000, CIN=64, HOPS=3, HID=256, COUT=64
// z layout: [N, 256] row-major; col-block k (64 wide) = hop-k embedding (k=0 is x).
// SPMM via on-device CSR grouped by destination (col): no float atomics.

#define ZW 256
#define NCH 64

// z[:,0:64] = x; deg = 0. Hop blocks of z are fully overwritten by CSR spmm.
__global__ void init_kernel(const float* __restrict__ x, float* __restrict__ z,
                            int* __restrict__ deg, int N) {
    int stride = gridDim.x * blockDim.x;
    int total4 = N * (NCH / 4);
    for (int idx = blockIdx.x * blockDim.x + threadIdx.x; idx < total4; idx += stride) {
        int n = idx >> 4;
        int c4 = idx & 15;
        reinterpret_cast<float4*>(z + (size_t)n * ZW)[c4] =
            reinterpret_cast<const float4*>(x + (size_t)n * NCH)[c4];
    }
    for (int idx = blockIdx.x * blockDim.x + threadIdx.x; idx < N; idx += stride)
        deg[idx] = 0;
}

__global__ void degree_kernel(const int* __restrict__ col, int* __restrict__ deg, int E) {
    int stride = gridDim.x * blockDim.x;
    for (int e = blockIdx.x * blockDim.x + threadIdx.x; e < E; e += stride)
        atomicAdd(&deg[col[e]], 1);
}

// Single-block exclusive scan over deg[N] -> offsets[N+1]; cursor = copy of offsets.
__global__ __launch_bounds__(1024) void scan_kernel(const int* __restrict__ deg,
                                                    int* __restrict__ offsets,
                                                    int* __restrict__ cursor, int N) {
    __shared__ int smem[1024];
    __shared__ int base;
    int tid = threadIdx.x;
    if (tid == 0) base = 0;
    __syncthreads();
    for (int start = 0; start < N; start += 1024) {
        int i = start + tid;
        int v = (i < N) ? deg[i] : 0;
        smem[tid] = v;
        __syncthreads();
        for (int off = 1; off < 1024; off <<= 1) {
            int t = (tid >= off) ? smem[tid - off] : 0;
            __syncthreads();
            smem[tid] += t;
            __syncthreads();
        }
        int excl = smem[tid] - v;
        int b = base;
        if (i < N) {
            offsets[i] = b + excl;
            cursor[i]  = b + excl;
        }
        __syncthreads();
        if (tid == 0) base += smem[1023];
        __syncthreads();
    }
    if (tid == 0) offsets[N] = base;
}

// Scatter edges into CSR slots; edge value computed inline.
__global__ void scatter_kernel(const int* __restrict__ row, const int* __restrict__ col,
                               const int* __restrict__ deg, int* __restrict__ cursor,
                               int2* __restrict__ meta, int E) {
    int stride = gridDim.x * blockDim.x;
    for (int e = blockIdx.x * blockDim.x + threadIdx.x; e < E; e += stride) {
        int r = row[e];
        int c = col[e];
        int dc = deg[c];
        int dr = deg[r];
        float v = 0.0f;
        if (dc > 0 && dr > 0) v = rsqrtf((float)(dc * dr));
        int pos = atomicAdd(&cursor[c], 1);
        meta[pos] = make_int2(r, __float_as_int(v));
    }
}

// One wave per destination node; lane = channel. No atomics: single coalesced store.
__global__ void spmm_csr_kernel(const int* __restrict__ offsets, const int2* __restrict__ meta,
                                const float* __restrict__ zin, float* __restrict__ zout, int N) {
    int lane = threadIdx.x & 63;
    int wave = (blockIdx.x * blockDim.x + threadIdx.x) >> 6;
    if (wave >= N) return;
    int start = offsets[wave];
    int end   = offsets[wave + 1];
    float acc = 0.0f;
    int j = start;
    for (; j + 2 <= end; j += 2) {
        int2 m0 = meta[j];
        int2 m1 = meta[j + 1];
        float h0 = zin[(size_t)m0.x * ZW + lane];
        float h1 = zin[(size_t)m1.x * ZW + lane];
        acc = fmaf(__int_as_float(m0.y), h0, acc);
        acc = fmaf(__int_as_float(m1.y), h1, acc);
    }
    if (j < end) {
        int2 m0 = meta[j];
        acc = fmaf(__int_as_float(m0.y), zin[(size_t)m0.x * ZW + lane], acc);
    }
    zout[(size_t)wave * ZW + lane] = acc;
}

// C[M,Ncol] = act(A[M,256] @ W[256,Ncol] + bias).  BM=BN=64, BK=16, 256 thr, 4x4/thread.
template <int RELU>
__global__ __launch_bounds__(256) void gemm_kernel(const float* __restrict__ A,
                                                   const float* __restrict__ W,
                                                   const float* __restrict__ bias,
                                                   float* __restrict__ C, int M, int Ncol) {
    const int K = 256;
    __shared__ float As[64][17];   // [m][k], +1 pad
    __shared__ float Bs[16][64];   // [k][n]

    int bm = blockIdx.y * 64;
    int bn = blockIdx.x * 64;
    int tid = threadIdx.x;
    int tx = tid & 15;
    int ty = tid >> 4;

    float acc[4][4] = {};

    int arow = tid >> 2;           // 0..63
    int aq   = (tid & 3) * 4;      // 0,4,8,12
    int brow = tid >> 4;           // 0..15
    int bq   = (tid & 15) * 4;     // 0..60

    for (int k0 = 0; k0 < K; k0 += 16) {
        float4 av = make_float4(0.f, 0.f, 0.f, 0.f);
        int gr = bm + arow;
        if (gr < M) av = *reinterpret_cast<const float4*>(A + (size_t)gr * K + k0 + aq);
        As[arow][aq + 0] = av.x;
        As[arow][aq + 1] = av.y;
        As[arow][aq + 2] = av.z;
        As[arow][aq + 3] = av.w;

        float4 bv = *reinterpret_cast<const float4*>(W + (size_t)(k0 + brow) * Ncol + bn + bq);
        *reinterpret_cast<float4*>(&Bs[brow][bq]) = bv;

        __syncthreads();

#pragma unroll
        for (int kk = 0; kk < 16; ++kk) {
            float a0 = As[ty * 4 + 0][kk];
            float a1 = As[ty * 4 + 1][kk];
            float a2 = As[ty * 4 + 2][kk];
            float a3 = As[ty * 4 + 3][kk];
            float b0 = Bs[kk][tx * 4 + 0];
            float b1 = Bs[kk][tx * 4 + 1];
            float b2 = Bs[kk][tx * 4 + 2];
            float b3 = Bs[kk][tx * 4 + 3];
            acc[0][0] += a0 * b0; acc[0][1] += a0 * b1; acc[0][2] += a0 * b2; acc[0][3] += a0 * b3;
            acc[1][0] += a1 * b0; acc[1][1] += a1 * b1; acc[1][2] += a1 * b2; acc[1][3] += a1 * b3;
            acc[2][0] += a2 * b0; acc[2][1] += a2 * b1; acc[2][2] += a2 * b2; acc[2][3] += a2 * b3;
            acc[3][0] += a3 * b0; acc[3][1] += a3 * b1; acc[3][2] += a3 * b2; acc[3][3] += a3 * b3;
        }
        __syncthreads();
    }

#pragma unroll
    for (int i = 0; i < 4; ++i) {
        int gr = bm + ty * 4 + i;
        if (gr >= M) continue;
#pragma unroll
        for (int j = 0; j < 4; ++j) {
            int gc = bn + tx * 4 + j;
            float v = acc[i][j] + bias[gc];
            if (RELU) v = fmaxf(v, 0.0f);
            C[(size_t)gr * Ncol + gc] = v;
        }
    }
}

extern "C" void kernel_launch(void* const* d_in, const int* in_sizes, int n_in,
                              void* d_out, int out_size, void* d_ws, size_t ws_size,
                              hipStream_t stream) {
    const float* x  = (const float*)d_in[0];
    const int* ei   = (const int*)d_in[1];
    const float* W0 = (const float*)d_in[2];
    const float* b0 = (const float*)d_in[3];
    const float* W1 = (const float*)d_in[4];
    const float* b1 = (const float*)d_in[5];
    const float* W2 = (const float*)d_in[6];
    const float* b2 = (const float*)d_in[7];
    float* out = (float*)d_out;

    const int N = in_sizes[0] / NCH;      // 50000
    const int E = in_sizes[1] / 2;        // 800000
    const int* row = ei;
    const int* col = ei + E;

    // workspace layout (floats/ints)
    float* z   = (float*)d_ws;                 // N*256 f
    float* zt  = z + (size_t)N * ZW;           // N*256 f (GEMM ping-pong)
    int*   deg = (int*)(zt + (size_t)N * ZW);  // N
    int*   off = deg + N;                      // N+1
    int*   cur = off + N + 1;                  // N
    // meta overlays zt: meta used only during CSR build + hops; zt only during GEMMs.
    int2*  meta = (int2*)zt;                   // E int2 = 6.4 MB < 51.2 MB

    const int TB = 256;

    init_kernel<<<2048, TB, 0, stream>>>(x, z, deg, N);
    degree_kernel<<<1024, TB, 0, stream>>>(col, deg, E);
    scan_kernel<<<1, 1024, 0, stream>>>(deg, off, cur, N);
    scatter_kernel<<<1024, TB, 0, stream>>>(row, col, deg, cur, meta, E);

    // 3 hops: hop k reads z col-block k-1, writes col-block k (one store per node)
    int spmm_blocks = (N * 64 + TB - 1) / TB;
    for (int hop = 1; hop <= 3; ++hop) {
        const float* zin = z + (hop - 1) * NCH;
        float* zout      = z + hop * NCH;
        spmm_csr_kernel<<<spmm_blocks, TB, 0, stream>>>(off, meta, zin, zout, N);
    }

    dim3 g1(ZW / 64, (N + 63) / 64);
    gemm_kernel<1><<<g1, TB, 0, stream>>>(z, W0, b0, zt, N, ZW);      // z  -> zt (relu)
    gemm_kernel<1><<<g1, TB, 0, stream>>>(zt, W1, b1, z, N, ZW);      // zt -> z  (relu)
    dim3 g3(NCH / 64, (N + 63) / 64);
    gemm_kernel<0><<<g3, TB, 0, stream>>>(z, W2, b2, out, N, NCH);    // z  -> out
}